// Round 13
// baseline (690.520 us; speedup 1.0000x reference)
//
#include <hip/hip_runtime.h>

typedef _Float16 f16;
typedef __attribute__((ext_vector_type(8))) _Float16 half8;
typedef __attribute__((ext_vector_type(2))) _Float16 half2v;
typedef __attribute__((ext_vector_type(4))) float float4v;

#define NNODES 50000
#define NEDGES 800000
#define NREL 8
#define NRSEG (NNODES * NREL)   // 400000 segments (dst, rel)
#define KDIM 1152               // (R+1)*128
#define CAP 16                  // bucket capacity: one 64B cacheline of indices
#define CAPQ (CAP / 4)
#define NT64 ((NNODES + 63) / 64)  // 782 tiles of 64 nodes
#define IMAX 0x7fffffff

// one kernel builds the whole edge structure: count + bucket scatter
__global__ void bucket_fill(const int* __restrict__ src, const int* __restrict__ dst,
                            const int* __restrict__ et, int* __restrict__ cnt,
                            int* __restrict__ esrc) {
    int e = blockIdx.x * blockDim.x + threadIdx.x;
    if (e < NEDGES) {
        int s = dst[e] * NREL + et[e];
        int p = atomicAdd(&cnt[s], 1);
        if (p < CAP) esrc[s * CAP + p] = src[e];
    }
}

// canonicalize bucket order: atomicAdd arrival order is nondeterministic
// run-to-run; fp16 accumulation is non-associative. Sorting each bucket makes
// every downstream sum a deterministic function of the inputs. Bonus (R9
// measured): ascending-id gather order cut FETCH_SIZE 171->102 MB.
__device__ __forceinline__ void ce(int& a, int& b) {
    int lo = min(a, b), hi = max(a, b);
    a = lo; b = hi;
}
__global__ void bucket_sort(const int* __restrict__ cnt, int* __restrict__ esrc) {
    int s = blockIdx.x * blockDim.x + threadIdx.x;
    if (s >= NRSEG) return;
    int len = cnt[s];
    len = len < CAP ? len : CAP;
    if (len < 2) return;
    int* b = esrc + (size_t)s * CAP;
    if (len <= 4) {
        int4 q = *(int4*)b;
        int v0 = q.x, v1 = len > 1 ? q.y : IMAX;
        int v2 = len > 2 ? q.z : IMAX, v3 = len > 3 ? q.w : IMAX;
        ce(v0, v1); ce(v2, v3); ce(v0, v2); ce(v1, v3); ce(v1, v2);
        *(int4*)b = (int4){v0, v1, v2, v3};  // pads (IMAX) are masked by len downstream
    } else if (len <= 8) {
        int4 qa = ((int4*)b)[0], qb = ((int4*)b)[1];
        int v0 = qa.x, v1 = qa.y, v2 = qa.z, v3 = qa.w;
        int v4 = qb.x, v5 = len > 5 ? qb.y : IMAX;
        int v6 = len > 6 ? qb.z : IMAX, v7 = len > 7 ? qb.w : IMAX;
        // Batcher odd-even mergesort, 8 elements (19 CE)
        ce(v0, v1); ce(v2, v3); ce(v4, v5); ce(v6, v7);
        ce(v0, v2); ce(v1, v3); ce(v4, v6); ce(v5, v7);
        ce(v1, v2); ce(v5, v6);
        ce(v0, v4); ce(v1, v5); ce(v2, v6); ce(v3, v7);
        ce(v2, v4); ce(v3, v5);
        ce(v1, v2); ce(v3, v4); ce(v5, v6);
        ((int4*)b)[0] = (int4){v0, v1, v2, v3};
        ((int4*)b)[1] = (int4){v4, v5, v6, v7};
    } else {
        // rare (~1e-4 of segments): insertion sort
        int v[CAP];
        for (int i = 0; i < len; ++i) v[i] = b[i];
        for (int i = 1; i < len; ++i) {
            int key = v[i], j = i - 1;
            while (j >= 0 && v[j] > key) { v[j + 1] = v[j]; --j; }
            v[j + 1] = key;
        }
        for (int i = 0; i < len; ++i) b[i] = v[i];
    }
}

// merged setup: x->fp16, weights->fp16 Bt, zero cnt, and zero the pad row
// (index NNODES) of the three activation buffers.
// Pad row = 128 f16 = 256 B = 16 int4 per buffer (48 threads total).
// R7/R8 BUG (fixed in R9, confirmed): over-long zeroing overran into Bt,
// racing the weight conversion -> determinism tripwire.
__global__ void setup_misc(const float* __restrict__ x, f16* __restrict__ x16,
                           const float* __restrict__ W1, const float* __restrict__ Wr1,
                           const float* __restrict__ W2, const float* __restrict__ Wr2,
                           const float* __restrict__ W3, const float* __restrict__ Wr3,
                           f16* __restrict__ Bt, int* __restrict__ cnt,
                           f16* __restrict__ ha, f16* __restrict__ hb) {
    int t = blockIdx.x * blockDim.x + threadIdx.x;
    if (t < NNODES * 64) {
        float2 v = ((const float2*)x)[t];
        half2v o = {(f16)v.x, (f16)v.y};
        ((half2v*)x16)[t] = o;
        return;
    }
    int idx = t - NNODES * 64;
    if (idx < 320 * KDIM) {
        int hg = idx / KDIM, k = idx - hg * KDIM;
        const float *W, *Wr;
        int h, H;
        if (hg < 128)      { W = W1; Wr = Wr1; h = hg;       H = 128; }
        else if (hg < 256) { W = W2; Wr = Wr2; h = hg - 128; H = 128; }
        else               { W = W3; Wr = Wr3; h = hg - 256; H = 64;  }
        float v = (k < 1024) ? W[(size_t)k * H + h] : Wr[(size_t)(k - 1024) * H + h];
        Bt[idx] = (f16)v;
        return;
    }
    int z = idx - 320 * KDIM;
    if (z < NRSEG / 4) {
        ((int4*)cnt)[z] = (int4){0, 0, 0, 0};
        return;
    }
    int z2 = z - NRSEG / 4;
    if (z2 < 48) {   // 3 buffers x 16 int4 = exactly one 128-f16 zero row each
        int row = z2 >> 4, qq = z2 & 15;
        f16* b = row == 0 ? x16 : (row == 1 ? ha : hb);
        ((int4*)(b + (size_t)NNODES * 128))[qq] = (int4){0, 0, 0, 0};
    }
}

// Fused RGCN layer — ALL-SLICES-RESIDENT, BARRIER-FREE slot loop.
// Block = (64-node tile, col-group of HB=32): 4 waves, wave w owns nodes
// [tile*64+16w, +16). grid = (NT64, H/HB).
// ALL 9 weight slices (8 rels + root) for this block's 32 cols are staged
// into LDS ONCE (9 x 32 x 128 f16 = 72 KB), one __syncthreads(), then the 9
// gather+MFMA slots run with ZERO barriers — no per-slot vmcnt drain, so the
// compiler overlaps slot r+1's bucket/row loads under slot r's MFMA.
// (R9/R11/R12 showed the 9 barrier-fenced phases were the serial critical
// path; every barrier forces a full vmcnt(0) drain.)
// Col-split x4 duplicates gather ISSUE but not L2-miss traffic (R1/R5
// evidence); VALU has headroom (12.6% at x1). LDS 72KB -> 2 blocks/CU =
// 8 waves/CU = R9's *achieved* occupancy.
// __launch_bounds__(256,2): VGPR cap 256 >> live set (spill-proof; the
// R4/R6/R10 spills all came from caps below the live set).
// MODE 0: bias+BN+ReLU -> fp16.  MODE 1: bias+sigmoid -> fp32.
template <int H, int HB, int MODE>
__global__ __launch_bounds__(256, 2) void fused_layer(
    const f16* __restrict__ act, const f16* __restrict__ Bt,
    const int* __restrict__ cnt, const int* __restrict__ esrc,
    const float* __restrict__ bias, const float* __restrict__ g,
    const float* __restrict__ be, const float* __restrict__ rm,
    const float* __restrict__ rv, f16* __restrict__ hout, float* __restrict__ fout) {
    constexpr int NT = HB / 16;          // col-tiles of 16 per block (2)
    constexpr int GPS = HB * 16;         // half8 granules per slice (512)
    constexpr int ITER = 9 * GPS / 256;  // staging iterations (18)
    __shared__ f16 Ws[9][HB][128];       // 72 KB: all slices resident
    const int tid = threadIdx.x;
    const int wave = tid >> 6, lane = tid & 63;
    const int l15 = lane & 15, quad = lane >> 4;
    const int m0 = blockIdx.x * 64 + wave * 16;  // this wave's 16 nodes
    const int nh = blockIdx.y;
    int node = m0 + l15;
    node = node < NNODES ? node : NNODES - 1;

    // ---- stage ALL 9 weight slices once (the only barrier follows) ----
#pragma unroll
    for (int i = 0; i < ITER; ++i) {
        int G = i * 256 + tid;           // [0, 9*GPS)
        int s = G / GPS;                 // slice 0..8 (8 = root: k offset 1024)
        int rem = G - s * GPS;
        int row = rem >> 4, gg = rem & 15;
        half8 v = *(const half8*)(Bt + (size_t)(nh * HB + row) * KDIM +
                                  s * 128 + gg * 8);
        *(half8*)&Ws[s][row][((gg ^ (row & 7))) * 8] = v;
    }

    // per-relation counts for this node (two int4, broadcast across quads)
    int4 cq0 = ((const int4*)cnt)[node * 2];
    int4 cq1 = ((const int4*)cnt)[node * 2 + 1];
    int cnts[8] = {cq0.x, cq0.y, cq0.z, cq0.w, cq1.x, cq1.y, cq1.z, cq1.w};
    const int4* bq_base = (const int4*)esrc + (size_t)node * NREL * CAPQ;

    float4v acc[NT];
#pragma unroll
    for (int j = 0; j < NT; ++j) acc[j] = (float4v){0.f, 0.f, 0.f, 0.f};

    __syncthreads();  // Ws visible; NO further barriers

    // ---- 9 slots, barrier-free: loads of slot r+1 overlap slot r's MFMA ----
#pragma unroll
    for (int r = 0; r < 9; ++r) {
        half8 ch[4];
#pragma unroll
        for (int t = 0; t < 4; ++t) ch[t] = (half8)(f16)0.f;
        if (r < 8) {
            int truelen = cnts[r];
            int len = truelen < CAP ? truelen : CAP;
            f16 invh = (f16)(truelen > 1 ? 1.f / (float)truelen : 1.f);
            const int4* bq = bq_base + r * CAPQ;
            for (int j4 = 0; j4 < (len + 3) >> 2; ++j4) {
                int4 q = bq[j4];
                int ids[4] = {q.x, q.y, q.z, q.w};
                int base = j4 * 4;
#pragma unroll
                for (int t = 0; t < 4; ++t) {
                    if (base + t < len) {
                        // 4 half8 loads at 64B stride; quads 0..3 tile each 64B chunk
                        const half8* rp = (const half8*)(act + (size_t)ids[t] * 128 + quad * 8);
                        half8 v0 = rp[0], v1 = rp[4], v2 = rp[8], v3 = rp[12];
                        ch[0] += v0;   // v_pk_add_f16 x4 each
                        ch[1] += v1;
                        ch[2] += v2;
                        ch[3] += v3;
                    }
                }
            }
            half8 sv;
#pragma unroll
            for (int u = 0; u < 8; ++u) sv[u] = invh;
#pragma unroll
            for (int t = 0; t < 4; ++t) ch[t] *= sv;  // v_pk_mul_f16
        } else {
            // root slot: own act row is the A-frag
#pragma unroll
            for (int ks = 0; ks < 4; ++ks)
                ch[ks] = *(const half8*)(act + (size_t)node * 128 + ks * 32 + quad * 8);
        }
        // ---- MFMA from resident LDS slice r ----
#pragma unroll
        for (int ks = 0; ks < 4; ++ks) {
#pragma unroll
            for (int nt = 0; nt < NT; ++nt) {
                int row = nt * 16 + l15;
                half8 bf = *(const half8*)&Ws[r][row][(((ks * 4 + quad) ^ (row & 7))) * 8];
                acc[nt] = __builtin_amdgcn_mfma_f32_16x16x32_f16(ch[ks], bf, acc[nt], 0, 0, 0);
            }
        }
    }

    // ---- epilogue: D[m = quad*4+rg][n = l15] per n-tile ----
#pragma unroll
    for (int nt = 0; nt < NT; ++nt) {
        int col = nh * HB + nt * 16 + l15;
        float alpha, beta;
        if (MODE == 0) {
            float sc = g[col] * rsqrtf(rv[col] + 1e-5f);
            alpha = sc;
            beta = (bias[col] - rm[col]) * sc + be[col];
        } else {
            alpha = 1.f;
            beta = bias[col];
        }
#pragma unroll
        for (int rg = 0; rg < 4; ++rg) {
            int row = m0 + quad * 4 + rg;
            if (row < NNODES) {
                float v = fmaf(acc[nt][rg], alpha, beta);
                if (MODE == 0) {
                    hout[(size_t)row * H + col] = (f16)fmaxf(v, 0.f);
                } else {
                    fout[(size_t)row * H + col] = 1.f / (1.f + __expf(-v));
                }
            }
        }
    }
}

extern "C" void kernel_launch(void* const* d_in, const int* in_sizes, int n_in,
                              void* d_out, int out_size, void* d_ws, size_t ws_size,
                              hipStream_t stream) {
    (void)in_sizes; (void)n_in; (void)out_size; (void)ws_size;
    const float* x   = (const float*)d_in[0];
    const int* ei    = (const int*)d_in[1];
    const int* et    = (const int*)d_in[2];
    const float* W1  = (const float*)d_in[3];
    const float* Wr1 = (const float*)d_in[4];
    const float* b1  = (const float*)d_in[5];
    const float* g1  = (const float*)d_in[6];
    const float* be1 = (const float*)d_in[7];
    const float* rm1 = (const float*)d_in[8];
    const float* rv1 = (const float*)d_in[9];
    const float* W2  = (const float*)d_in[10];
    const float* Wr2 = (const float*)d_in[11];
    const float* b2  = (const float*)d_in[12];
    const float* g2  = (const float*)d_in[13];
    const float* be2 = (const float*)d_in[14];
    const float* rm2 = (const float*)d_in[15];
    const float* rv2 = (const float*)d_in[16];
    const float* W3  = (const float*)d_in[17];
    const float* Wr3 = (const float*)d_in[18];
    const float* b3  = (const float*)d_in[19];
    const int* src = ei;
    const int* dst = ei + NEDGES;
    float* out = (float*)d_out;

    char* ws = (char*)d_ws;
    size_t off = 0;
    auto alloc = [&](size_t bytes) -> void* {
        off = (off + 255) & ~(size_t)255;
        void* p = ws + off;
        off += bytes;
        return p;
    };
    int* cnt  = (int*)alloc((size_t)NRSEG * 4);                  // 1.6 MB
    int* esrc = (int*)alloc((size_t)NRSEG * CAP * 4);            // 25.6 MB
    f16* x16  = (f16*)alloc((size_t)(NNODES + 1) * 128 * 2);     // +1 zero pad row
    f16* ha   = (f16*)alloc((size_t)(NNODES + 1) * 128 * 2);
    f16* hb   = (f16*)alloc((size_t)(NNODES + 1) * 128 * 2);
    f16* Bt   = (f16*)alloc((size_t)320 * KDIM * 2);             // 0.74 MB (L1|L2|L3)

    // setup (also zeroes cnt + pad rows) must precede bucket_fill
    const int SETUP_T = NNODES * 64 + 320 * KDIM + NRSEG / 4 + 48;
    setup_misc<<<(SETUP_T + 255) / 256, 256, 0, stream>>>(
        x, x16, W1, Wr1, W2, Wr2, W3, Wr3, Bt, cnt, ha, hb);
    bucket_fill<<<(NEDGES + 255) / 256, 256, 0, stream>>>(src, dst, et, cnt, esrc);
    bucket_sort<<<(NRSEG + 255) / 256, 256, 0, stream>>>(cnt, esrc);

    fused_layer<128, 32, 0><<<dim3(NT64, 4), 256, 0, stream>>>(x16, Bt, cnt, esrc,
                                                               b1, g1, be1, rm1, rv1, ha, nullptr);
    fused_layer<128, 32, 0><<<dim3(NT64, 4), 256, 0, stream>>>(ha, Bt + (size_t)128 * KDIM, cnt, esrc,
                                                               b2, g2, be2, rm2, rv2, hb, nullptr);
    fused_layer<64, 32, 1><<<dim3(NT64, 2), 256, 0, stream>>>(hb, Bt + (size_t)256 * KDIM, cnt, esrc,
                                                              b3, nullptr, nullptr, nullptr, nullptr,
                                                              nullptr, out);
}

// Round 14
// 447.069 us; speedup vs baseline: 1.5446x; 1.5446x over previous
//
#include <hip/hip_runtime.h>

typedef _Float16 f16;
typedef __attribute__((ext_vector_type(8))) _Float16 half8;
typedef __attribute__((ext_vector_type(2))) _Float16 half2v;
typedef __attribute__((ext_vector_type(4))) float float4v;

#define NNODES 50000
#define NEDGES 800000
#define NREL 8
#define NRSEG (NNODES * NREL)   // 400000 segments (dst, rel)
#define KDIM 1152               // (R+1)*128
#define CAP 16                  // bucket capacity: one 64B cacheline of indices
#define CAPQ (CAP / 4)
#define NT64 ((NNODES + 63) / 64)  // 782 tiles of 64 nodes
#define IMAX 0x7fffffff

// one kernel builds the whole edge structure: count + bucket scatter
__global__ void bucket_fill(const int* __restrict__ src, const int* __restrict__ dst,
                            const int* __restrict__ et, int* __restrict__ cnt,
                            int* __restrict__ esrc) {
    int e = blockIdx.x * blockDim.x + threadIdx.x;
    if (e < NEDGES) {
        int s = dst[e] * NREL + et[e];
        int p = atomicAdd(&cnt[s], 1);
        if (p < CAP) esrc[s * CAP + p] = src[e];
    }
}

// canonicalize bucket order: atomicAdd arrival order is nondeterministic
// run-to-run; fp16 accumulation is non-associative. Sorting each bucket makes
// every downstream sum a deterministic function of the inputs. Bonus (R9
// measured): ascending-id gather order cut FETCH_SIZE 171->102 MB.
__device__ __forceinline__ void ce(int& a, int& b) {
    int lo = min(a, b), hi = max(a, b);
    a = lo; b = hi;
}
__global__ void bucket_sort(const int* __restrict__ cnt, int* __restrict__ esrc) {
    int s = blockIdx.x * blockDim.x + threadIdx.x;
    if (s >= NRSEG) return;
    int len = cnt[s];
    len = len < CAP ? len : CAP;
    if (len < 2) return;
    int* b = esrc + (size_t)s * CAP;
    if (len <= 4) {
        int4 q = *(int4*)b;
        int v0 = q.x, v1 = len > 1 ? q.y : IMAX;
        int v2 = len > 2 ? q.z : IMAX, v3 = len > 3 ? q.w : IMAX;
        ce(v0, v1); ce(v2, v3); ce(v0, v2); ce(v1, v3); ce(v1, v2);
        *(int4*)b = (int4){v0, v1, v2, v3};  // pads (IMAX) are masked by len downstream
    } else if (len <= 8) {
        int4 qa = ((int4*)b)[0], qb = ((int4*)b)[1];
        int v0 = qa.x, v1 = qa.y, v2 = qa.z, v3 = qa.w;
        int v4 = qb.x, v5 = len > 5 ? qb.y : IMAX;
        int v6 = len > 6 ? qb.z : IMAX, v7 = len > 7 ? qb.w : IMAX;
        // Batcher odd-even mergesort, 8 elements (19 CE)
        ce(v0, v1); ce(v2, v3); ce(v4, v5); ce(v6, v7);
        ce(v0, v2); ce(v1, v3); ce(v4, v6); ce(v5, v7);
        ce(v1, v2); ce(v5, v6);
        ce(v0, v4); ce(v1, v5); ce(v2, v6); ce(v3, v7);
        ce(v2, v4); ce(v3, v5);
        ce(v1, v2); ce(v3, v4); ce(v5, v6);
        ((int4*)b)[0] = (int4){v0, v1, v2, v3};
        ((int4*)b)[1] = (int4){v4, v5, v6, v7};
    } else {
        // rare (~1e-4 of segments): insertion sort
        int v[CAP];
        for (int i = 0; i < len; ++i) v[i] = b[i];
        for (int i = 1; i < len; ++i) {
            int key = v[i], j = i - 1;
            while (j >= 0 && v[j] > key) { v[j + 1] = v[j]; --j; }
            v[j + 1] = key;
        }
        for (int i = 0; i < len; ++i) b[i] = v[i];
    }
}

// merged setup: x->fp16, weights->fp16 Bt, zero cnt, and zero the pad row
// (index NNODES) of the three activation buffers.
// Pad row = 128 f16 = 256 B = 16 int4 per buffer (48 threads total).
// R7/R8 BUG (fixed in R9, confirmed): over-long zeroing overran into Bt,
// racing the weight conversion -> determinism tripwire.
__global__ void setup_misc(const float* __restrict__ x, f16* __restrict__ x16,
                           const float* __restrict__ W1, const float* __restrict__ Wr1,
                           const float* __restrict__ W2, const float* __restrict__ Wr2,
                           const float* __restrict__ W3, const float* __restrict__ Wr3,
                           f16* __restrict__ Bt, int* __restrict__ cnt,
                           f16* __restrict__ ha, f16* __restrict__ hb) {
    int t = blockIdx.x * blockDim.x + threadIdx.x;
    if (t < NNODES * 64) {
        float2 v = ((const float2*)x)[t];
        half2v o = {(f16)v.x, (f16)v.y};
        ((half2v*)x16)[t] = o;
        return;
    }
    int idx = t - NNODES * 64;
    if (idx < 320 * KDIM) {
        int hg = idx / KDIM, k = idx - hg * KDIM;
        const float *W, *Wr;
        int h, H;
        if (hg < 128)      { W = W1; Wr = Wr1; h = hg;       H = 128; }
        else if (hg < 256) { W = W2; Wr = Wr2; h = hg - 128; H = 128; }
        else               { W = W3; Wr = Wr3; h = hg - 256; H = 64;  }
        float v = (k < 1024) ? W[(size_t)k * H + h] : Wr[(size_t)(k - 1024) * H + h];
        Bt[idx] = (f16)v;
        return;
    }
    int z = idx - 320 * KDIM;
    if (z < NRSEG / 4) {
        ((int4*)cnt)[z] = (int4){0, 0, 0, 0};
        return;
    }
    int z2 = z - NRSEG / 4;
    if (z2 < 48) {   // 3 buffers x 16 int4 = exactly one 128-f16 zero row each
        int row = z2 >> 4, qq = z2 & 15;
        f16* b = row == 0 ? x16 : (row == 1 ? ha : hb);
        ((int4*)(b + (size_t)NNODES * 128))[qq] = (int4){0, 0, 0, 0};
    }
}

// Fused RGCN layer — R9 structure + ISSUE-EARLY BRANCHLESS gather.
// Merged columns (single gather/node), packed-fp16 accumulation, sorted
// buckets (deterministic). Block = 64-node tile x ALL H cols, grid (NT64,1).
// 4 waves, wave w owns nodes [tile*64+16w, +16).
// KEY CHANGE vs R9: the 2-deep head pipeline now carries BOTH bucket int4s
// (qp = ids 0-3, qs = ids 4-7), so at phase start ALL ids of the current slot
// are already in registers. All 8 rows issue branchless back-to-back (invalid
// -> zero pad row at index NNODES), then ONE wait + tree of v_pk_add_f16 —
// the phase's in-phase dependent chain (bucket int4 -> rows -> wait, per
// group, R9's measured ~10K-cyc/phase stall) collapses to ~one row latency
// overlapped with weight staging. Tail only for len>8 (P~0.1%).
// __launch_bounds__(256,2): VGPR cap 256 >> ~220 live (8 rows x 4 half8 =
// 128 + acc 32 + misc) -> spill-impossible; 2 blocks/CU cap = R9's ACHIEVED
// residency, so nothing is lost.
// MODE 0: bias+BN+ReLU -> fp16.  MODE 1: bias+sigmoid -> fp32.
template <int H, int HB, int MODE>
__global__ __launch_bounds__(256, 2) void fused_layer(
    const f16* __restrict__ act, const f16* __restrict__ Bt,
    const int* __restrict__ cnt, const int* __restrict__ esrc,
    const float* __restrict__ bias, const float* __restrict__ g,
    const float* __restrict__ be, const float* __restrict__ rm,
    const float* __restrict__ rv, f16* __restrict__ hout, float* __restrict__ fout) {
    constexpr int NT = HB / 16;          // col-tiles of 16 per block
    __shared__ f16 Ws[HB][128];          // 16/32 KB, XOR-swizzled granules
    const int tid = threadIdx.x;
    const int wave = tid >> 6, lane = tid & 63;
    const int l15 = lane & 15, quad = lane >> 4;
    const int m0 = blockIdx.x * 64 + wave * 16;  // this wave's 16 nodes
    const int nh = blockIdx.y;
    int node = m0 + l15;
    node = node < NNODES ? node : NNODES - 1;

    // per-relation counts for this node (two int4, broadcast across quads)
    int4 cq0 = ((const int4*)cnt)[node * 2];
    int4 cq1 = ((const int4*)cnt)[node * 2 + 1];
    int cnts[8] = {cq0.x, cq0.y, cq0.z, cq0.w, cq1.x, cq1.y, cq1.z, cq1.w};
    const int4* bq_base = (const int4*)esrc + (size_t)node * NREL * CAPQ;

    float4v acc[NT];
#pragma unroll
    for (int j = 0; j < NT; ++j) acc[j] = (float4v){0.f, 0.f, 0.f, 0.f};

    // 2-deep pipeline of BOTH bucket int4s (ids 0-3 and 4-7)
    int4 qp0 = bq_base[0];
    int4 qs0 = bq_base[1];
    int4 qp1 = bq_base[CAPQ];
    int4 qs1 = bq_base[CAPQ + 1];

#pragma unroll
    for (int r = 0; r < 9; ++r) {
        __syncthreads();  // all waves done reading Ws of slot r-1
        // ---- cooperative stage of weight slice r into swizzled LDS ----
#pragma unroll
        for (int i = 0; i < NT; ++i) {
            int G = i * 256 + tid;       // granule id: row = G>>4, g = G&15
            int row = G >> 4, gg = G & 15;
            half8 v = *(const half8*)(Bt + (size_t)(nh * HB + row) * KDIM +
                                      r * 128 + gg * 8);
            *(half8*)&Ws[row][((gg ^ (row & 7))) * 8] = v;
        }
        // ---- gather: all 8 ids in regs, issue rows branchless, one wait ----
        half8 ch[4];
#pragma unroll
        for (int t = 0; t < 4; ++t) ch[t] = (half8)(f16)0.f;
        if (r < 8) {
            int truelen = cnts[r];
            int len = truelen < CAP ? truelen : CAP;
            f16 invh = (f16)(truelen > 1 ? 1.f / (float)truelen : 1.f);
            int4 q0 = qp0, s0 = qs0;
            qp0 = qp1; qs0 = qs1;
            if (r < 6) {  // prefetch heads 2 slots ahead
                qp1 = bq_base[(r + 2) * CAPQ];
                qs1 = bq_base[(r + 2) * CAPQ + 1];
            }
            int id[8];
            id[0] = len > 0 ? q0.x : NNODES;
            id[1] = len > 1 ? q0.y : NNODES;
            id[2] = len > 2 ? q0.z : NNODES;
            id[3] = len > 3 ? q0.w : NNODES;
            id[4] = len > 4 ? s0.x : NNODES;
            id[5] = len > 5 ? s0.y : NNODES;
            id[6] = len > 6 ? s0.z : NNODES;
            id[7] = len > 7 ? s0.w : NNODES;
            half8 rv0[8], rv1[8], rv2[8], rv3[8];
#pragma unroll
            for (int k = 0; k < 8; ++k) {
                // 4 half8 loads at 64B stride; quads 0..3 tile each 64B chunk
                const half8* rp = (const half8*)(act + (size_t)id[k] * 128 + quad * 8);
                rv0[k] = rp[0]; rv1[k] = rp[4]; rv2[k] = rp[8]; rv3[k] = rp[12];
            }
            ch[0] = ((rv0[0] + rv0[1]) + (rv0[2] + rv0[3])) +
                    ((rv0[4] + rv0[5]) + (rv0[6] + rv0[7]));
            ch[1] = ((rv1[0] + rv1[1]) + (rv1[2] + rv1[3])) +
                    ((rv1[4] + rv1[5]) + (rv1[6] + rv1[7]));
            ch[2] = ((rv2[0] + rv2[1]) + (rv2[2] + rv2[3])) +
                    ((rv2[4] + rv2[5]) + (rv2[6] + rv2[7]));
            ch[3] = ((rv3[0] + rv3[1]) + (rv3[2] + rv3[3])) +
                    ((rv3[4] + rv3[5]) + (rv3[6] + rv3[7]));
            // tail (len>8, P~0.1%): R9-style loop from j4=2
            if (len > 8) {
                const int4* bq = bq_base + r * CAPQ;
                for (int j4 = 2; j4 < (len + 3) >> 2; ++j4) {
                    int4 q = bq[j4];
                    int ids4[4] = {q.x, q.y, q.z, q.w};
                    int base = j4 * 4;
#pragma unroll
                    for (int t = 0; t < 4; ++t) {
                        if (base + t < len) {
                            const half8* rp = (const half8*)(act + (size_t)ids4[t] * 128 + quad * 8);
                            half8 v0 = rp[0], v1 = rp[4], v2 = rp[8], v3 = rp[12];
                            ch[0] += v0; ch[1] += v1; ch[2] += v2; ch[3] += v3;
                        }
                    }
                }
            }
            half8 sv;
#pragma unroll
            for (int u = 0; u < 8; ++u) sv[u] = invh;
#pragma unroll
            for (int t = 0; t < 4; ++t) ch[t] *= sv;  // v_pk_mul_f16
        } else {
            // root slot: own act row is the A-frag
#pragma unroll
            for (int ks = 0; ks < 4; ++ks)
                ch[ks] = *(const half8*)(act + (size_t)node * 128 + ks * 32 + quad * 8);
        }
        __syncthreads();  // Ws visible
        // ---- MFMA from LDS ----
#pragma unroll
        for (int ks = 0; ks < 4; ++ks) {
#pragma unroll
            for (int nt = 0; nt < NT; ++nt) {
                int row = nt * 16 + l15;
                half8 bf = *(const half8*)&Ws[row][(((ks * 4 + quad) ^ (row & 7))) * 8];
                acc[nt] = __builtin_amdgcn_mfma_f32_16x16x32_f16(ch[ks], bf, acc[nt], 0, 0, 0);
            }
        }
    }

    // ---- epilogue: D[m = quad*4+rg][n = l15] per n-tile ----
#pragma unroll
    for (int nt = 0; nt < NT; ++nt) {
        int col = nh * HB + nt * 16 + l15;
        float alpha, beta;
        if (MODE == 0) {
            float sc = g[col] * rsqrtf(rv[col] + 1e-5f);
            alpha = sc;
            beta = (bias[col] - rm[col]) * sc + be[col];
        } else {
            alpha = 1.f;
            beta = bias[col];
        }
#pragma unroll
        for (int rg = 0; rg < 4; ++rg) {
            int row = m0 + quad * 4 + rg;
            if (row < NNODES) {
                float v = fmaf(acc[nt][rg], alpha, beta);
                if (MODE == 0) {
                    hout[(size_t)row * H + col] = (f16)fmaxf(v, 0.f);
                } else {
                    fout[(size_t)row * H + col] = 1.f / (1.f + __expf(-v));
                }
            }
        }
    }
}

extern "C" void kernel_launch(void* const* d_in, const int* in_sizes, int n_in,
                              void* d_out, int out_size, void* d_ws, size_t ws_size,
                              hipStream_t stream) {
    (void)in_sizes; (void)n_in; (void)out_size; (void)ws_size;
    const float* x   = (const float*)d_in[0];
    const int* ei    = (const int*)d_in[1];
    const int* et    = (const int*)d_in[2];
    const float* W1  = (const float*)d_in[3];
    const float* Wr1 = (const float*)d_in[4];
    const float* b1  = (const float*)d_in[5];
    const float* g1  = (const float*)d_in[6];
    const float* be1 = (const float*)d_in[7];
    const float* rm1 = (const float*)d_in[8];
    const float* rv1 = (const float*)d_in[9];
    const float* W2  = (const float*)d_in[10];
    const float* Wr2 = (const float*)d_in[11];
    const float* b2  = (const float*)d_in[12];
    const float* g2  = (const float*)d_in[13];
    const float* be2 = (const float*)d_in[14];
    const float* rm2 = (const float*)d_in[15];
    const float* rv2 = (const float*)d_in[16];
    const float* W3  = (const float*)d_in[17];
    const float* Wr3 = (const float*)d_in[18];
    const float* b3  = (const float*)d_in[19];
    const int* src = ei;
    const int* dst = ei + NEDGES;
    float* out = (float*)d_out;

    char* ws = (char*)d_ws;
    size_t off = 0;
    auto alloc = [&](size_t bytes) -> void* {
        off = (off + 255) & ~(size_t)255;
        void* p = ws + off;
        off += bytes;
        return p;
    };
    int* cnt  = (int*)alloc((size_t)NRSEG * 4);                  // 1.6 MB
    int* esrc = (int*)alloc((size_t)NRSEG * CAP * 4);            // 25.6 MB
    f16* x16  = (f16*)alloc((size_t)(NNODES + 1) * 128 * 2);     // +1 zero pad row
    f16* ha   = (f16*)alloc((size_t)(NNODES + 1) * 128 * 2);
    f16* hb   = (f16*)alloc((size_t)(NNODES + 1) * 128 * 2);
    f16* Bt   = (f16*)alloc((size_t)320 * KDIM * 2);             // 0.74 MB (L1|L2|L3)

    // setup (also zeroes cnt + pad rows) must precede bucket_fill
    const int SETUP_T = NNODES * 64 + 320 * KDIM + NRSEG / 4 + 48;
    setup_misc<<<(SETUP_T + 255) / 256, 256, 0, stream>>>(
        x, x16, W1, Wr1, W2, Wr2, W3, Wr3, Bt, cnt, ha, hb);
    bucket_fill<<<(NEDGES + 255) / 256, 256, 0, stream>>>(src, dst, et, cnt, esrc);
    bucket_sort<<<(NRSEG + 255) / 256, 256, 0, stream>>>(cnt, esrc);

    fused_layer<128, 128, 0><<<dim3(NT64, 1), 256, 0, stream>>>(x16, Bt, cnt, esrc,
                                                                b1, g1, be1, rm1, rv1, ha, nullptr);
    fused_layer<128, 128, 0><<<dim3(NT64, 1), 256, 0, stream>>>(ha, Bt + (size_t)128 * KDIM, cnt, esrc,
                                                                b2, g2, be2, rm2, rv2, hb, nullptr);
    fused_layer<64, 64, 1><<<dim3(NT64, 1), 256, 0, stream>>>(hb, Bt + (size_t)256 * KDIM, cnt, esrc,
                                                              b3, nullptr, nullptr, nullptr, nullptr,
                                                              nullptr, out);
}

// Round 15
// 386.972 us; speedup vs baseline: 1.7844x; 1.1553x over previous
//
#include <hip/hip_runtime.h>

typedef _Float16 f16;
typedef __attribute__((ext_vector_type(8))) _Float16 half8;
typedef __attribute__((ext_vector_type(2))) _Float16 half2v;
typedef __attribute__((ext_vector_type(4))) float float4v;

#define NNODES 50000
#define NEDGES 800000
#define NREL 8
#define NRSEG (NNODES * NREL)   // 400000 segments (dst, rel)
#define KDIM 1152               // (R+1)*128
#define CAP 16                  // bucket capacity: one 64B cacheline of indices
#define CAPQ (CAP / 4)
#define NT64 ((NNODES + 63) / 64)  // 782 tiles of 64 nodes
#define IMAX 0x7fffffff

// one kernel builds the whole edge structure: count + bucket scatter
__global__ void bucket_fill(const int* __restrict__ src, const int* __restrict__ dst,
                            const int* __restrict__ et, int* __restrict__ cnt,
                            int* __restrict__ esrc) {
    int e = blockIdx.x * blockDim.x + threadIdx.x;
    if (e < NEDGES) {
        int s = dst[e] * NREL + et[e];
        int p = atomicAdd(&cnt[s], 1);
        if (p < CAP) esrc[s * CAP + p] = src[e];
    }
}

// canonicalize bucket order: atomicAdd arrival order is nondeterministic
// run-to-run; fp16 accumulation is non-associative. Sorting each bucket makes
// every downstream sum a deterministic function of the inputs. Bonus (R9
// measured): ascending-id gather order cut FETCH_SIZE 171->102 MB.
__device__ __forceinline__ void ce(int& a, int& b) {
    int lo = min(a, b), hi = max(a, b);
    a = lo; b = hi;
}
__global__ void bucket_sort(const int* __restrict__ cnt, int* __restrict__ esrc) {
    int s = blockIdx.x * blockDim.x + threadIdx.x;
    if (s >= NRSEG) return;
    int len = cnt[s];
    len = len < CAP ? len : CAP;
    if (len < 2) return;
    int* b = esrc + (size_t)s * CAP;
    if (len <= 4) {
        int4 q = *(int4*)b;
        int v0 = q.x, v1 = len > 1 ? q.y : IMAX;
        int v2 = len > 2 ? q.z : IMAX, v3 = len > 3 ? q.w : IMAX;
        ce(v0, v1); ce(v2, v3); ce(v0, v2); ce(v1, v3); ce(v1, v2);
        *(int4*)b = (int4){v0, v1, v2, v3};  // pads (IMAX) are masked by len downstream
    } else if (len <= 8) {
        int4 qa = ((int4*)b)[0], qb = ((int4*)b)[1];
        int v0 = qa.x, v1 = qa.y, v2 = qa.z, v3 = qa.w;
        int v4 = qb.x, v5 = len > 5 ? qb.y : IMAX;
        int v6 = len > 6 ? qb.z : IMAX, v7 = len > 7 ? qb.w : IMAX;
        // Batcher odd-even mergesort, 8 elements (19 CE)
        ce(v0, v1); ce(v2, v3); ce(v4, v5); ce(v6, v7);
        ce(v0, v2); ce(v1, v3); ce(v4, v6); ce(v5, v7);
        ce(v1, v2); ce(v5, v6);
        ce(v0, v4); ce(v1, v5); ce(v2, v6); ce(v3, v7);
        ce(v2, v4); ce(v3, v5);
        ce(v1, v2); ce(v3, v4); ce(v5, v6);
        ((int4*)b)[0] = (int4){v0, v1, v2, v3};
        ((int4*)b)[1] = (int4){v4, v5, v6, v7};
    } else {
        // rare (~1e-4 of segments): insertion sort
        int v[CAP];
        for (int i = 0; i < len; ++i) v[i] = b[i];
        for (int i = 1; i < len; ++i) {
            int key = v[i], j = i - 1;
            while (j >= 0 && v[j] > key) { v[j + 1] = v[j]; --j; }
            v[j + 1] = key;
        }
        for (int i = 0; i < len; ++i) b[i] = v[i];
    }
}

// merged setup: x->fp16, weights->fp16 Bt, zero cnt, and zero the pad row
// (index NNODES) of the three activation buffers.
// Pad row = 128 f16 = 256 B = 16 int4 per buffer (48 threads total).
// R7/R8 BUG (fixed in R9, confirmed): over-long zeroing overran into Bt,
// racing the weight conversion -> determinism tripwire.
__global__ void setup_misc(const float* __restrict__ x, f16* __restrict__ x16,
                           const float* __restrict__ W1, const float* __restrict__ Wr1,
                           const float* __restrict__ W2, const float* __restrict__ Wr2,
                           const float* __restrict__ W3, const float* __restrict__ Wr3,
                           f16* __restrict__ Bt, int* __restrict__ cnt,
                           f16* __restrict__ ha, f16* __restrict__ hb) {
    int t = blockIdx.x * blockDim.x + threadIdx.x;
    if (t < NNODES * 64) {
        float2 v = ((const float2*)x)[t];
        half2v o = {(f16)v.x, (f16)v.y};
        ((half2v*)x16)[t] = o;
        return;
    }
    int idx = t - NNODES * 64;
    if (idx < 320 * KDIM) {
        int hg = idx / KDIM, k = idx - hg * KDIM;
        const float *W, *Wr;
        int h, H;
        if (hg < 128)      { W = W1; Wr = Wr1; h = hg;       H = 128; }
        else if (hg < 256) { W = W2; Wr = Wr2; h = hg - 128; H = 128; }
        else               { W = W3; Wr = Wr3; h = hg - 256; H = 64;  }
        float v = (k < 1024) ? W[(size_t)k * H + h] : Wr[(size_t)(k - 1024) * H + h];
        Bt[idx] = (f16)v;
        return;
    }
    int z = idx - 320 * KDIM;
    if (z < NRSEG / 4) {
        ((int4*)cnt)[z] = (int4){0, 0, 0, 0};
        return;
    }
    int z2 = z - NRSEG / 4;
    if (z2 < 48) {   // 3 buffers x 16 int4 = exactly one 128-f16 zero row each
        int row = z2 >> 4, qq = z2 & 15;
        f16* b = row == 0 ? x16 : (row == 1 ? ha : hb);
        ((int4*)(b + (size_t)NNODES * 128))[qq] = (int4){0, 0, 0, 0};
    }
}

// Fused RGCN layer — WAVE-LEVEL RELATION-SPLIT (512 threads/block).
// Block = 64-node tile x ALL H cols. 8 waves in two groups over the SAME
// nodes: group 0 (waves 0-3) handles relations 0-3 + root, group 1 (waves
// 4-7) handles relations 4-7. Wave wv of each group owns nodes
// [tile*64+16*wv, +16). Each phase p (0..3) stages BOTH slices (p, 4+p)
// cooperatively into Ws[2][H][128] and the two groups gather CONCURRENTLY
// on different waves — latency overlap with R9's exact per-wave gather body,
// zero extra registers, zero duplicated traffic (relation partition).
// Serial barrier-phases: 9 -> 5. Phase 4: grp0 stages root + does root MFMA;
// grp1 writes its fp32 partial into LDS (aliases dead Ws[1], fixed order ->
// deterministic); grp0 combines + epilogue.
// LDS 64KB -> 2 blocks/CU = 16-wave cap (R9 achieved 7.8).
// __launch_bounds__(512,4): VGPR target 128 >> ~70 live -> no spill.
// MODE 0: bias+BN+ReLU -> fp16.  MODE 1: bias+sigmoid -> fp32.
template <int H, int MODE>
__global__ __launch_bounds__(512, 4) void fused_layer(
    const f16* __restrict__ act, const f16* __restrict__ Bt,
    const int* __restrict__ cnt, const int* __restrict__ esrc,
    const float* __restrict__ bias, const float* __restrict__ g,
    const float* __restrict__ be, const float* __restrict__ rm,
    const float* __restrict__ rv, f16* __restrict__ hout, float* __restrict__ fout) {
    constexpr int NT = H / 16;           // col-tiles of 16
    constexpr int GPS = H * 16;          // half8 granules per slice
    __shared__ f16 Ws[2][H][128];        // 64/32 KB: two slices per phase
    float* AccS = (float*)&Ws[1][0][0];  // aliases Ws[1] after last read (16/32 KB)
    const int tid = threadIdx.x;
    const int wave = tid >> 6, lane = tid & 63;
    const int grp = wave >> 2, wv = wave & 3;
    const int l15 = lane & 15, quad = lane >> 4;
    const int m0 = blockIdx.x * 64 + wv * 16;  // this wave's 16 nodes
    int node = m0 + l15;
    node = node < NNODES ? node : NNODES - 1;

    // this group's 4 relation counts (slot0 = grp*4)
    const int slot0 = grp * 4;
    int4 cq = ((const int4*)cnt)[node * 2 + grp];
    int mycnt[4] = {cq.x, cq.y, cq.z, cq.w};
    const int4* bq_base = (const int4*)esrc + (size_t)node * NREL * CAPQ;

    float4v acc[NT];
#pragma unroll
    for (int j = 0; j < NT; ++j) acc[j] = (float4v){0.f, 0.f, 0.f, 0.f};

    // 2-deep pipeline of this group's bucket heads
    int4 qp0 = bq_base[slot0 * CAPQ];
    int4 qp1 = bq_base[(slot0 + 1) * CAPQ];

#pragma unroll
    for (int p = 0; p < 4; ++p) {
        __syncthreads();  // Ws of phase p-1 fully read
        // ---- cooperative stage of slice pair (p, 4+p), all 512 threads ----
#pragma unroll
        for (int i = 0; i < 2 * GPS / 512; ++i) {
            int G = i * 512 + tid;       // [0, 2*GPS)
            int s = G / GPS;
            int rem = G - s * GPS;
            int row = rem >> 4, gg = rem & 15;
            half8 v = *(const half8*)(Bt + (size_t)row * KDIM +
                                      (p + s * 4) * 128 + gg * 8);
            *(half8*)&Ws[s][row][((gg ^ (row & 7))) * 8] = v;
        }
        // ---- gather this group's slot (R9-proven body) ----
        half8 ch[4];
#pragma unroll
        for (int t = 0; t < 4; ++t) ch[t] = (half8)(f16)0.f;
        {
            int truelen = mycnt[p];
            int len = truelen < CAP ? truelen : CAP;
            f16 invh = (f16)(truelen > 1 ? 1.f / (float)truelen : 1.f);
            const int4* bq = bq_base + (slot0 + p) * CAPQ;
            int4 q0 = qp0;
            qp0 = qp1;
            if (p < 2) qp1 = bq_base[(slot0 + p + 2) * CAPQ];  // prefetch 2 ahead
            for (int j4 = 0; j4 < (len + 3) >> 2; ++j4) {
                int4 q = (j4 == 0) ? q0 : bq[j4];
                int ids[4] = {q.x, q.y, q.z, q.w};
                int base = j4 * 4;
#pragma unroll
                for (int t = 0; t < 4; ++t) {
                    if (base + t < len) {
                        // 4 half8 loads at 64B stride; quads 0..3 tile each 64B chunk
                        const half8* rp = (const half8*)(act + (size_t)ids[t] * 128 + quad * 8);
                        half8 v0 = rp[0], v1 = rp[4], v2 = rp[8], v3 = rp[12];
                        ch[0] += v0;   // v_pk_add_f16 x4 each
                        ch[1] += v1;
                        ch[2] += v2;
                        ch[3] += v3;
                    }
                }
            }
            half8 sv;
#pragma unroll
            for (int u = 0; u < 8; ++u) sv[u] = invh;
#pragma unroll
            for (int t = 0; t < 4; ++t) ch[t] *= sv;  // v_pk_mul_f16
        }
        __syncthreads();  // Ws visible
        // ---- MFMA from this group's slice ----
#pragma unroll
        for (int ks = 0; ks < 4; ++ks) {
#pragma unroll
            for (int nt = 0; nt < NT; ++nt) {
                int row = nt * 16 + l15;
                half8 bf = *(const half8*)&Ws[grp][row][(((ks * 4 + quad) ^ (row & 7))) * 8];
                acc[nt] = __builtin_amdgcn_mfma_f32_16x16x32_f16(ch[ks], bf, acc[nt], 0, 0, 0);
            }
        }
    }

    // ---- phase 4: root (grp0) + partial handoff (grp1) ----
    __syncthreads();  // all reads of Ws[0]/Ws[1] done
    half8 chr[4];
    if (grp == 0) {
        // root A-frag: own act row (issue early, overlaps staging)
#pragma unroll
        for (int ks = 0; ks < 4; ++ks)
            chr[ks] = *(const half8*)(act + (size_t)node * 128 + ks * 32 + quad * 8);
        // grp0's 256 threads stage the root slice into Ws[0]
#pragma unroll
        for (int i = 0; i < GPS / 256; ++i) {
            int G = i * 256 + tid;       // tid in [0,256)
            int row = G >> 4, gg = G & 15;
            half8 v = *(const half8*)(Bt + (size_t)row * KDIM + 1024 + gg * 8);
            *(half8*)&Ws[0][row][((gg ^ (row & 7))) * 8] = v;
        }
    } else {
        // grp1 writes its fp32 partial into AccS (aliases dead Ws[1])
#pragma unroll
        for (int nt = 0; nt < NT; ++nt)
#pragma unroll
            for (int rg = 0; rg < 4; ++rg)
                AccS[(wv * 16 + quad * 4 + rg) * H + nt * 16 + l15] = acc[nt][rg];
    }
    __syncthreads();  // root slice + partial visible

    if (grp == 0) {
        // root MFMA
#pragma unroll
        for (int ks = 0; ks < 4; ++ks) {
#pragma unroll
            for (int nt = 0; nt < NT; ++nt) {
                int row = nt * 16 + l15;
                half8 bf = *(const half8*)&Ws[0][row][(((ks * 4 + quad) ^ (row & 7))) * 8];
                acc[nt] = __builtin_amdgcn_mfma_f32_16x16x32_f16(chr[ks], bf, acc[nt], 0, 0, 0);
            }
        }
        // ---- epilogue: combine with grp1 partial, then BN/activation ----
#pragma unroll
        for (int nt = 0; nt < NT; ++nt) {
            int col = nt * 16 + l15;
            float alpha, beta;
            if (MODE == 0) {
                float sc = g[col] * rsqrtf(rv[col] + 1e-5f);
                alpha = sc;
                beta = (bias[col] - rm[col]) * sc + be[col];
            } else {
                alpha = 1.f;
                beta = bias[col];
            }
#pragma unroll
            for (int rg = 0; rg < 4; ++rg) {
                int row = m0 + quad * 4 + rg;
                if (row < NNODES) {
                    float tot = acc[nt][rg] +
                                AccS[(wv * 16 + quad * 4 + rg) * H + nt * 16 + l15];
                    float v = fmaf(tot, alpha, beta);
                    if (MODE == 0) {
                        hout[(size_t)row * H + col] = (f16)fmaxf(v, 0.f);
                    } else {
                        fout[(size_t)row * H + col] = 1.f / (1.f + __expf(-v));
                    }
                }
            }
        }
    }
}

extern "C" void kernel_launch(void* const* d_in, const int* in_sizes, int n_in,
                              void* d_out, int out_size, void* d_ws, size_t ws_size,
                              hipStream_t stream) {
    (void)in_sizes; (void)n_in; (void)out_size; (void)ws_size;
    const float* x   = (const float*)d_in[0];
    const int* ei    = (const int*)d_in[1];
    const int* et    = (const int*)d_in[2];
    const float* W1  = (const float*)d_in[3];
    const float* Wr1 = (const float*)d_in[4];
    const float* b1  = (const float*)d_in[5];
    const float* g1  = (const float*)d_in[6];
    const float* be1 = (const float*)d_in[7];
    const float* rm1 = (const float*)d_in[8];
    const float* rv1 = (const float*)d_in[9];
    const float* W2  = (const float*)d_in[10];
    const float* Wr2 = (const float*)d_in[11];
    const float* b2  = (const float*)d_in[12];
    const float* g2  = (const float*)d_in[13];
    const float* be2 = (const float*)d_in[14];
    const float* rm2 = (const float*)d_in[15];
    const float* rv2 = (const float*)d_in[16];
    const float* W3  = (const float*)d_in[17];
    const float* Wr3 = (const float*)d_in[18];
    const float* b3  = (const float*)d_in[19];
    const int* src = ei;
    const int* dst = ei + NEDGES;
    float* out = (float*)d_out;

    char* ws = (char*)d_ws;
    size_t off = 0;
    auto alloc = [&](size_t bytes) -> void* {
        off = (off + 255) & ~(size_t)255;
        void* p = ws + off;
        off += bytes;
        return p;
    };
    int* cnt  = (int*)alloc((size_t)NRSEG * 4);                  // 1.6 MB
    int* esrc = (int*)alloc((size_t)NRSEG * CAP * 4);            // 25.6 MB
    f16* x16  = (f16*)alloc((size_t)(NNODES + 1) * 128 * 2);     // +1 zero pad row
    f16* ha   = (f16*)alloc((size_t)(NNODES + 1) * 128 * 2);
    f16* hb   = (f16*)alloc((size_t)(NNODES + 1) * 128 * 2);
    f16* Bt   = (f16*)alloc((size_t)320 * KDIM * 2);             // 0.74 MB (L1|L2|L3)

    // setup (also zeroes cnt + pad rows) must precede bucket_fill
    const int SETUP_T = NNODES * 64 + 320 * KDIM + NRSEG / 4 + 48;
    setup_misc<<<(SETUP_T + 255) / 256, 256, 0, stream>>>(
        x, x16, W1, Wr1, W2, Wr2, W3, Wr3, Bt, cnt, ha, hb);
    bucket_fill<<<(NEDGES + 255) / 256, 256, 0, stream>>>(src, dst, et, cnt, esrc);
    bucket_sort<<<(NRSEG + 255) / 256, 256, 0, stream>>>(cnt, esrc);

    fused_layer<128, 0><<<NT64, 512, 0, stream>>>(x16, Bt, cnt, esrc,
                                                  b1, g1, be1, rm1, rv1, ha, nullptr);
    fused_layer<128, 0><<<NT64, 512, 0, stream>>>(ha, Bt + (size_t)128 * KDIM, cnt, esrc,
                                                  b2, g2, be2, rm2, rv2, hb, nullptr);
    fused_layer<64, 1><<<NT64, 512, 0, stream>>>(hb, Bt + (size_t)256 * KDIM, cnt, esrc,
                                                 b3, nullptr, nullptr, nullptr, nullptr,
                                                 nullptr, out);
}